// Round 5
// baseline (427.186 us; speedup 1.0000x reference)
//
#include <hip/hip_runtime.h>
#include <hip/hip_bf16.h>
#include <stdint.h>

// out = ReLU((din*mask + bias*mask) @ W). din [8192,4096] fp32 ~10% dense,
// W [4096,4096] fp32 row-major (K = rows), bias [4096].
// R7: prep_a (16 elems/thread) + transpose_w (64x64 LDS tile) -- unchanged.
// R8: coarse 2-deep counted-vmcnt pipeline -> REGRESSED (131.6 vs 123), exactly
//     m196's "coarse phase-split hurts" prediction. Ledger proven race-free.
// R9: same ledger, FINE 4-phase interior per K-tile (m201 pattern):
//   P1: ds_read af_lo(8)+bf(8) | barrier | lgkm0 | 16 MFMA (mf0-3 x nf0-1) | barrier
//   P2: ds_read af_hi(8)       | barrier | lgkm0 | 16 MFMA (mf0-3 x nf2-3) | barrier
//       -- after P2's trailing barrier, EVERY wave has retired all slot-s
//          ds_reads (its lgkm0 preceded the barrier) => slot s free.
//   P3: stage A-half of tile t+2 (4 gload_lds) + 16 MFMA (mf4-7 x nf0-1)
//   P4: stage B-half            (4 gload_lds) + 16 MFMA (mf4-7 x nf2-3)
//   vmcnt never drains to 0 in the main loop; entry vmcnt(8)+barrier retires
//   exactly tile t (8 loads/tile/wave, oldest-first). Final tile peeled, vmcnt(0).
//   i32 accumulation exact => absmax unchanged (1.5).

#define M_ROWS 8192
#define N_COLS 4096
#define K_DIM  4096

#define BM 256
#define BN 256
#define BK 128              // i8 elements per K-tile (128 bytes per row)
#define NT (K_DIM / BK)     // 32 K-tiles

typedef int int32x4_t __attribute__((ext_vector_type(4)));

#define SA (8.0f / 127.0f)
#define SW (1.0f / 127.0f)
#define INV_SA (127.0f / 8.0f)
#define INV_SW 127.0f
#define DEQ (SA * SW)

__device__ __forceinline__ void gload_lds16(const void* gsrc, void* ldst) {
  // 16B per lane, LDS dest = wave-uniform base + lane*16 (hardware rule).
  __builtin_amdgcn_global_load_lds(
      (const __attribute__((address_space(1))) uint32_t*)gsrc,
      (__attribute__((address_space(3))) uint32_t*)ldst,
      16, 0, 0);
}

__device__ __forceinline__ int quant_i8(float x, float inv_s) {
  float q = fminf(fmaxf(x * inv_s, -127.f), 127.f);
  return (int)lrintf(q);
}

// A_i8[b,j] = q(din != 0 ? din + bias[j] : 0); 16 elems/thread, one int4 store.
__global__ __launch_bounds__(256)
void prep_a(const float* __restrict__ din, const float* __restrict__ bias,
            int32x4_t* __restrict__ Ai8) {
  const int64_t t16 = (int64_t)blockIdx.x * 256 + threadIdx.x;  // 16-elem group
  const int64_t e0 = t16 * 16;
  const int j0 = (int)(e0 & (K_DIM - 1));
  const float4* dp = (const float4*)(din + e0);
  const float4* bp = (const float4*)(bias + j0);
  int out[4];
#pragma unroll
  for (int c = 0; c < 4; ++c) {
    float4 d = dp[c];
    float4 bv = bp[c];
    int q0 = quant_i8(d.x != 0.f ? d.x + bv.x : 0.f, INV_SA);
    int q1 = quant_i8(d.y != 0.f ? d.y + bv.y : 0.f, INV_SA);
    int q2 = quant_i8(d.z != 0.f ? d.z + bv.z : 0.f, INV_SA);
    int q3 = quant_i8(d.w != 0.f ? d.w + bv.w : 0.f, INV_SA);
    out[c] = (q0 & 0xff) | ((q1 & 0xff) << 8) | ((q2 & 0xff) << 16) | ((q3 & 0xff) << 24);
  }
  Ai8[t16] = (int32x4_t){out[0], out[1], out[2], out[3]};
}

// Wt_i8[n,j] = q(W[j,n]) via 64x64 LDS tile; 16B contiguous int4 writes.
__global__ __launch_bounds__(256)
void transpose_w(const float* __restrict__ W, char* __restrict__ Wt) {
  __shared__ __align__(16) float tile[64][68];
  const int tid = threadIdx.x;
  const int n0 = blockIdx.x * 64;
  const int j0 = blockIdx.y * 64;
#pragma unroll
  for (int c = 0; c < 4; ++c) {
    const int idx = c * 256 + tid;
    const int r = idx >> 4;
    const int q = idx & 15;
    float4 v = *(const float4*)(W + (int64_t)(j0 + r) * K_DIM + (n0 + q * 4));
    *(float4*)&tile[r][q * 4] = v;
  }
  __syncthreads();
  const int n = tid >> 2;
  const int jc = (tid & 3) * 16;
  int w[4];
#pragma unroll
  for (int d = 0; d < 4; ++d) {
    int q0 = quant_i8(tile[jc + d * 4 + 0][n], INV_SW);
    int q1 = quant_i8(tile[jc + d * 4 + 1][n], INV_SW);
    int q2 = quant_i8(tile[jc + d * 4 + 2][n], INV_SW);
    int q3 = quant_i8(tile[jc + d * 4 + 3][n], INV_SW);
    w[d] = (q0 & 0xff) | ((q1 & 0xff) << 8) | ((q2 & 0xff) << 16) | ((q3 & 0xff) << 24);
  }
  *(int32x4_t*)(Wt + (int64_t)(n0 + n) * K_DIM + j0 + jc) =
      (int32x4_t){w[0], w[1], w[2], w[3]};
}

// ---- GEMM helper macros (textual expansion => all indices compile-time) ----
// A frag: row = wm*128 + (MB+mi)*16 + l16; B frag: row = wn*64 + nf*16 + l16.
// Byte pos within 128B row for kstep ks: ((ks*4+quad)^(l16&7))*16.
#define A_ADDR(SLOT, MF, KS) \
  (const int32x4_t*)(lds + (SLOT) * 65536 + (wm * 128 + (MF) * 16 + l16) * BK + \
                     ((((KS) << 2) + quad) ^ r7) * 16)
#define B_ADDR(SLOT, NF, KS) \
  (const int32x4_t*)(lds + (SLOT) * 65536 + 32768 + (wn * 64 + (NF) * 16 + l16) * BK + \
                     ((((KS) << 2) + quad) ^ r7) * 16)

#define READ_AF(DST, SLOT, MB)                      \
  _Pragma("unroll") for (int mi = 0; mi < 4; ++mi)  \
  _Pragma("unroll") for (int ks = 0; ks < 2; ++ks)  \
      DST[mi][ks] = *A_ADDR(SLOT, (MB) + mi, ks);

#define READ_BF(SLOT)                               \
  _Pragma("unroll") for (int ni = 0; ni < 4; ++ni)  \
  _Pragma("unroll") for (int ks = 0; ks < 2; ++ks)  \
      bf[ni][ks] = *B_ADDR(SLOT, ni, ks);

// One C-quadrant over full BK: 4mf x 2nf x 2ks = 16 MFMA, setprio-wrapped (T5).
#define QUAD_MFMA(AARR, MB, NB)                                                \
  do {                                                                         \
    __builtin_amdgcn_s_setprio(1);                                             \
    _Pragma("unroll") for (int mi = 0; mi < 4; ++mi)                           \
    _Pragma("unroll") for (int ni = 0; ni < 2; ++ni)                           \
    _Pragma("unroll") for (int ks = 0; ks < 2; ++ks)                           \
        acc[(MB) + mi][(NB) + ni] = __builtin_amdgcn_mfma_i32_16x16x64_i8(     \
            AARR[mi][ks], bf[(NB) + ni][ks], acc[(MB) + mi][(NB) + ni], 0, 0, 0); \
    __builtin_amdgcn_s_setprio(0);                                             \
  } while (0)

#define WAIT_LGKM0()                                  \
  do {                                                \
    asm volatile("s_waitcnt lgkmcnt(0)" ::: "memory");\
    __builtin_amdgcn_sched_barrier(0);                \
  } while (0)

// C[M,N] = relu(A[M,K] * Bt[N,K]^T) * DEQ, i8 in / fp32 out.
__global__ __launch_bounds__(512, 2)
void gemm_i8_relu(const char* __restrict__ A, const char* __restrict__ Bt,
                  float* __restrict__ C) {
  // [slot 0: A 32K | B 32K][slot 1: A 32K | B 32K]
  __shared__ __align__(16) char lds[131072];

  const int tid = threadIdx.x;   // 0..511
  const int wave = tid >> 6;     // 0..7
  const int lane = tid & 63;
  const int wm = wave >> 2;      // 0..1  (M-wave)
  const int wn = wave & 3;       // 0..3  (N-wave)
  const int quad = lane >> 4;
  const int l16 = lane & 15;
  const int r7 = l16 & 7;        // row&7 of every fragment row (bases mult. of 8)

  // Bijective XCD swizzle: 512 blocks = 8 XCDs x 64 contiguous.
  const int lin = blockIdx.y * 16 + blockIdx.x;
  const int lin2 = (lin & 7) * 64 + (lin >> 3);
  const int bm = lin2 >> 4;      // 0..31
  const int bn = lin2 & 15;      // 0..15

  // Staging: tile = 32KB/matrix = 32 ops of 1KB (64 lanes x 16B); op o covers
  // rows [o*8, o*8+8). Wave issues ops o = wave*4+i; 4 A + 4 B = 8 vmem/tile
  // (the vmcnt(8) unit). Swizzle: lane fetches global chunk (l%8)^(l/8) of its
  // 128B row -> LDS slot (row, pos p) holds chunk p^(row&7); same 128B global
  // segment, so coalescing unchanged.
  const int lrow8 = lane >> 3;
  const int lchunk = lane & 7;
  const int swz = lchunk ^ lrow8;

  const char* aCur[4];
  const char* bCur[4];
  char* aDst[4];
  char* bDst[4];
#pragma unroll
  for (int i = 0; i < 4; ++i) {
    const int o = wave * 4 + i;  // 0..31
    aCur[i] = A + (int64_t)(bm * BM + o * 8 + lrow8) * K_DIM + swz * 16;
    bCur[i] = Bt + (int64_t)(bn * BN + o * 8 + lrow8) * K_DIM + swz * 16;
    aDst[i] = lds + o * 1024 + lane * 16;          // + slot*65536
    bDst[i] = lds + 32768 + o * 1024 + lane * 16;  // + slot*65536
  }

  auto stage_a = [&](int slot) {
#pragma unroll
    for (int i = 0; i < 4; ++i) {
      gload_lds16(aCur[i], aDst[i] + slot * 65536);
      aCur[i] += BK;
    }
  };
  auto stage_b = [&](int slot) {
#pragma unroll
    for (int i = 0; i < 4; ++i) {
      gload_lds16(bCur[i], bDst[i] + slot * 65536);
      bCur[i] += BK;
    }
  };

  int32x4_t acc[8][4];
#pragma unroll
  for (int mf = 0; mf < 8; ++mf)
#pragma unroll
    for (int nf = 0; nf < 4; ++nf)
      acc[mf][nf] = (int32x4_t){0, 0, 0, 0};

  int32x4_t af_lo[4][2], af_hi[4][2], bf[4][2];

  // Prologue: stage tiles 0 and 1 (A then B per tile; 16 vmem outstanding).
  stage_a(0); stage_b(0);
  stage_a(1); stage_b(1);

  // Ledger: at iter t's entry, outstanding = tile t (8) + tile t+1 (8);
  // vmcnt(8) retires exactly tile t (oldest-first). Iter t stages t+2.
  for (int t = 0; t < NT - 1; ++t) {
    const int s = t & 1;
    asm volatile("s_waitcnt vmcnt(8)" ::: "memory");
    __builtin_amdgcn_s_barrier();

    // ---- P1 ----
    READ_AF(af_lo, s, 0);
    READ_BF(s);
    __builtin_amdgcn_s_barrier();
    WAIT_LGKM0();
    QUAD_MFMA(af_lo, 0, 0);
    __builtin_amdgcn_s_barrier();

    // ---- P2 ----
    READ_AF(af_hi, s, 4);
    __builtin_amdgcn_s_barrier();
    WAIT_LGKM0();
    QUAD_MFMA(af_lo, 0, 2);
    __builtin_amdgcn_s_barrier();
    // All waves' slot-s ds_reads retired before this barrier => slot s free.

    // ---- P3: stage A-half of tile t+2, register-resident MFMA ----
    if (t + 2 < NT) stage_a(s);
    QUAD_MFMA(af_hi, 4, 0);

    // ---- P4: stage B-half, register-resident MFMA ----
    if (t + 2 < NT) stage_b(s);
    QUAD_MFMA(af_hi, 4, 2);
  }

  // Peeled final tile (t = NT-1, slot 1): only its 8 loads outstanding.
  asm volatile("s_waitcnt vmcnt(0)" ::: "memory");
  __builtin_amdgcn_s_barrier();
  READ_AF(af_lo, 1, 0);
  READ_BF(1);
  WAIT_LGKM0();
  QUAD_MFMA(af_lo, 0, 0);
  READ_AF(af_hi, 1, 4);
  WAIT_LGKM0();
  QUAD_MFMA(af_lo, 0, 2);
  QUAD_MFMA(af_hi, 4, 0);
  QUAD_MFMA(af_hi, 4, 2);

  // Epilogue: C/D layout col=lane&15, row=quad*4+reg (dtype-independent).
#pragma unroll
  for (int mf = 0; mf < 8; ++mf) {
#pragma unroll
    for (int nf = 0; nf < 4; ++nf) {
      const int col = bn * BN + wn * 64 + nf * 16 + l16;
      const int row0 = bm * BM + wm * 128 + mf * 16 + quad * 4;
#pragma unroll
      for (int i = 0; i < 4; ++i) {
        int vi = acc[mf][nf][i];
        float v = (float)(vi > 0 ? vi : 0) * DEQ;
        C[(int64_t)(row0 + i) * N_COLS + col] = v;
      }
    }
  }
}

extern "C" void kernel_launch(void* const* d_in, const int* in_sizes, int n_in,
                              void* d_out, int out_size, void* d_ws, size_t ws_size,
                              hipStream_t stream) {
  const float* din = (const float*)d_in[0];     // [8192, 4096] fp32
  const float* weight = (const float*)d_in[1];  // [4096, 4096] fp32
  const float* bias = (const float*)d_in[2];    // [4096] fp32
  float* out = (float*)d_out;                   // [8192, 4096] fp32

  int32x4_t* Ai8 = (int32x4_t*)d_ws;                           // 33.6 MB
  char* Wt = (char*)d_ws + (size_t)M_ROWS * K_DIM;             // +16.8 MB

  prep_a<<<M_ROWS * K_DIM / 4096, 256, 0, stream>>>(din, bias, Ai8);
  transpose_w<<<dim3(N_COLS / 64, K_DIM / 64), 256, 0, stream>>>(weight, (char*)Wt);
  gemm_i8_relu<<<dim3(N_COLS / BN, M_ROWS / BM), 512, 0, stream>>>(
      (const char*)Ai8, (const char*)Wt, out);
}

// Round 6
// 387.851 us; speedup vs baseline: 1.1014x; 1.1014x over previous
//
#include <hip/hip_runtime.h>
#include <hip/hip_bf16.h>
#include <stdint.h>

// out = ReLU((din*mask + bias*mask) @ W). din [8192,4096] fp32 ~10% dense,
// W [4096,4096] fp32 row-major (K = rows), bias [4096].
// R7: prep_a (16 elems/thread) + transpose_w (64x64 LDS tile) -- unchanged.
// R8 (coarse 2-deep pipeline): 131.6 us, REGRESSED. R9 (fine 4-phase, 1 blk/CU):
//   176.3 us, REGRESSED -- 5 barriers/K-tile with no co-resident block to hide
//   them. Both reverted.
// R10: back to R4's proven 2-phase 128^2 structure (123 us, 3 blocks/CU,
//   0 bank conflicts) with ONE change: MFMA 16x16x64 -> 32x32x32 i8.
//   - +11.7% measured rate (4404 vs 3944 TOPS), half the MFMA instructions.
//   - Fragment family preserved: lane holds row = lane&31, k-chunk
//     (ks*2 + (lane>>5)); row&7 = lane&7, so the same XOR swizzle
//     (chunk c of row r at position c^(r&7)) serves both shapes.
//   - C/D layout (m74/m101-verified): col = lane&31,
//     row = (reg&3) + 8*(reg>>2) + 4*(lane>>5).
//   i32 accumulation exact => absmax must stay 1.5 (deviation = layout bug).

#define M_ROWS 8192
#define N_COLS 4096
#define K_DIM  4096

#define BM 128
#define BN 128
#define BK 128  // i8 elements per K-tile (128 bytes per row)

typedef int int32x4_t __attribute__((ext_vector_type(4)));
typedef int int32x16_t __attribute__((ext_vector_type(16)));

#define SA (8.0f / 127.0f)
#define SW (1.0f / 127.0f)
#define INV_SA (127.0f / 8.0f)
#define INV_SW 127.0f
#define DEQ (SA * SW)

__device__ __forceinline__ void gload_lds16(const void* gsrc, void* ldst) {
  // 16B per lane, LDS dest = wave-uniform base + lane*16 (hardware rule).
  __builtin_amdgcn_global_load_lds(
      (const __attribute__((address_space(1))) uint32_t*)gsrc,
      (__attribute__((address_space(3))) uint32_t*)ldst,
      16, 0, 0);
}

__device__ __forceinline__ int quant_i8(float x, float inv_s) {
  float q = fminf(fmaxf(x * inv_s, -127.f), 127.f);
  return (int)lrintf(q);
}

// A_i8[b,j] = q(din != 0 ? din + bias[j] : 0); 16 elems/thread, one int4 store.
__global__ __launch_bounds__(256)
void prep_a(const float* __restrict__ din, const float* __restrict__ bias,
            int32x4_t* __restrict__ Ai8) {
  const int64_t t16 = (int64_t)blockIdx.x * 256 + threadIdx.x;  // 16-elem group
  const int64_t e0 = t16 * 16;
  const int j0 = (int)(e0 & (K_DIM - 1));
  const float4* dp = (const float4*)(din + e0);
  const float4* bp = (const float4*)(bias + j0);
  int out[4];
#pragma unroll
  for (int c = 0; c < 4; ++c) {
    float4 d = dp[c];
    float4 bv = bp[c];
    int q0 = quant_i8(d.x != 0.f ? d.x + bv.x : 0.f, INV_SA);
    int q1 = quant_i8(d.y != 0.f ? d.y + bv.y : 0.f, INV_SA);
    int q2 = quant_i8(d.z != 0.f ? d.z + bv.z : 0.f, INV_SA);
    int q3 = quant_i8(d.w != 0.f ? d.w + bv.w : 0.f, INV_SA);
    out[c] = (q0 & 0xff) | ((q1 & 0xff) << 8) | ((q2 & 0xff) << 16) | ((q3 & 0xff) << 24);
  }
  Ai8[t16] = (int32x4_t){out[0], out[1], out[2], out[3]};
}

// Wt_i8[n,j] = q(W[j,n]) via 64x64 LDS tile; 16B contiguous int4 writes.
__global__ __launch_bounds__(256)
void transpose_w(const float* __restrict__ W, char* __restrict__ Wt) {
  __shared__ __align__(16) float tile[64][68];
  const int tid = threadIdx.x;
  const int n0 = blockIdx.x * 64;
  const int j0 = blockIdx.y * 64;
#pragma unroll
  for (int c = 0; c < 4; ++c) {
    const int idx = c * 256 + tid;
    const int r = idx >> 4;
    const int q = idx & 15;
    float4 v = *(const float4*)(W + (int64_t)(j0 + r) * K_DIM + (n0 + q * 4));
    *(float4*)&tile[r][q * 4] = v;
  }
  __syncthreads();
  const int n = tid >> 2;
  const int jc = (tid & 3) * 16;
  int w[4];
#pragma unroll
  for (int d = 0; d < 4; ++d) {
    int q0 = quant_i8(tile[jc + d * 4 + 0][n], INV_SW);
    int q1 = quant_i8(tile[jc + d * 4 + 1][n], INV_SW);
    int q2 = quant_i8(tile[jc + d * 4 + 2][n], INV_SW);
    int q3 = quant_i8(tile[jc + d * 4 + 3][n], INV_SW);
    w[d] = (q0 & 0xff) | ((q1 & 0xff) << 8) | ((q2 & 0xff) << 16) | ((q3 & 0xff) << 24);
  }
  *(int32x4_t*)(Wt + (int64_t)(n0 + n) * K_DIM + j0 + jc) =
      (int32x4_t){w[0], w[1], w[2], w[3]};
}

// C[M,N] = relu(A[M,K] * Bt[N,K]^T) * DEQ, i8 in / fp32 out.
// 256 threads = 4 waves (2x2), each wave 64x64 via 2x2 of 32x32x32 MFMA.
__global__ __launch_bounds__(256, 3)
void gemm_i8_relu(const char* __restrict__ A, const char* __restrict__ Bt,
                  float* __restrict__ C) {
  __shared__ __align__(16) char As[BM * BK];  // 16 KB
  __shared__ __align__(16) char Bs[BN * BK];  // 16 KB

  const int tid = threadIdx.x;
  const int wave = tid >> 6;
  const int lane = tid & 63;
  const int wm = wave >> 1;      // 0..1
  const int wn = wave & 1;       // 0..1
  const int r31 = lane & 31;     // fragment row within 32-row tile
  const int half = lane >> 5;    // k-half within 32-wide K-slice
  const int r7 = lane & 7;       // row&7 (tile bases are multiples of 32)

  const int bm = blockIdx.y;
  const int bn = blockIdx.x;

  // Staging (UNCHANGED from R4): 16 ops/matrix of 1 KB (64 lanes x 16B);
  // op o covers rows [o*8,o*8+8). lane l fetches global chunk (l%8)^(l/8) of
  // its 128B row -> LDS slot (row, pos p) holds chunk p^(row&7). Same global
  // 128B segment per op => coalescing unchanged; measured 0 bank conflicts.
  const int lrow8 = lane >> 3;   // 0..7
  const int lchunk = lane & 7;   // 0..7
  const int swz = lchunk ^ lrow8;

  const char* aSrc[4];
  const char* bSrc[4];
  char* aDst[4];
  char* bDst[4];
#pragma unroll
  for (int i = 0; i < 4; ++i) {
    const int o = wave * 4 + i;  // op 0..15
    aSrc[i] = A + (int64_t)(bm * BM + o * 8 + lrow8) * K_DIM + swz * 16;
    bSrc[i] = Bt + (int64_t)(bn * BN + o * 8 + lrow8) * K_DIM + swz * 16;
    aDst[i] = As + o * 1024 + lane * 16;
    bDst[i] = Bs + o * 1024 + lane * 16;
  }

  int32x16_t acc[2][2];
#pragma unroll
  for (int m = 0; m < 2; ++m)
#pragma unroll
    for (int n = 0; n < 2; ++n)
#pragma unroll
      for (int e = 0; e < 16; ++e)
        acc[m][n][e] = 0;

  for (int kt = 0; kt < K_DIM / BK; ++kt) {
    __syncthreads();  // previous iteration's ds_reads done before overwrite
#pragma unroll
    for (int i = 0; i < 4; ++i) {
      gload_lds16(aSrc[i], aDst[i]);
      gload_lds16(bSrc[i], bDst[i]);
      aSrc[i] += BK;
      bSrc[i] += BK;
    }
    __syncthreads();  // staging visible

    // 4 k-steps of K=32. Lane needs 16B chunk kc = ks*2 + half of its row,
    // stored at position kc ^ (row&7).
#pragma unroll
    for (int ks = 0; ks < 4; ++ks) {
      const int pos = ((ks * 2 + half) ^ r7) * 16;
      int32x4_t af[2], bf[2];
#pragma unroll
      for (int m = 0; m < 2; ++m)
        af[m] = *(const int32x4_t*)(As + (wm * 64 + m * 32 + r31) * BK + pos);
#pragma unroll
      for (int n = 0; n < 2; ++n)
        bf[n] = *(const int32x4_t*)(Bs + (wn * 64 + n * 32 + r31) * BK + pos);
#pragma unroll
      for (int m = 0; m < 2; ++m)
#pragma unroll
        for (int n = 0; n < 2; ++n)
          acc[m][n] = __builtin_amdgcn_mfma_i32_32x32x32_i8(af[m], bf[n],
                                                            acc[m][n], 0, 0, 0);
    }
  }

  // Epilogue: 32x32 C/D layout (m74/m101-verified, dtype-independent):
  // col = lane&31, row = (reg&3) + 8*(reg>>2) + 4*(lane>>5). ReLU fused.
#pragma unroll
  for (int m = 0; m < 2; ++m) {
#pragma unroll
    for (int n = 0; n < 2; ++n) {
      const int col = bn * BN + wn * 64 + n * 32 + r31;
      const int rbase = bm * BM + wm * 64 + m * 32 + 4 * half;
#pragma unroll
      for (int reg = 0; reg < 16; ++reg) {
        const int row = rbase + (reg & 3) + 8 * (reg >> 2);
        int vi = acc[m][n][reg];
        float v = (float)(vi > 0 ? vi : 0) * DEQ;
        C[(int64_t)row * N_COLS + col] = v;
      }
    }
  }
}

extern "C" void kernel_launch(void* const* d_in, const int* in_sizes, int n_in,
                              void* d_out, int out_size, void* d_ws, size_t ws_size,
                              hipStream_t stream) {
  const float* din = (const float*)d_in[0];     // [8192, 4096] fp32
  const float* weight = (const float*)d_in[1];  // [4096, 4096] fp32
  const float* bias = (const float*)d_in[2];    // [4096] fp32
  float* out = (float*)d_out;                   // [8192, 4096] fp32

  int32x4_t* Ai8 = (int32x4_t*)d_ws;                           // 33.6 MB
  char* Wt = (char*)d_ws + (size_t)M_ROWS * K_DIM;             // +16.8 MB

  prep_a<<<M_ROWS * K_DIM / 4096, 256, 0, stream>>>(din, bias, Ai8);
  transpose_w<<<dim3(N_COLS / 64, K_DIM / 64), 256, 0, stream>>>(weight, (char*)Wt);
  gemm_i8_relu<<<dim3(N_COLS / BN, M_ROWS / BM), 256, 0, stream>>>(
      (const char*)Ai8, (const char*)Wt, out);
}